// Round 17
// baseline (1284.857 us; speedup 1.0000x reference)
//
#include <hip/hip_runtime.h>
#include <hip/hip_bf16.h>
#include <math.h>

typedef __attribute__((ext_vector_type(4))) float f32x4;
typedef __attribute__((ext_vector_type(8))) short s16x8;
typedef __attribute__((ext_vector_type(4))) unsigned short u16x4;

#define MFMA16(a, b, c) __builtin_amdgcn_mfma_f32_16x16x32_bf16(a, b, c, 0, 0, 0)

static constexpr int BB = 32, TT = 128, EE = 512, HH = 1024, VV = 32000;
static constexpr int FH = 4 * HH;           // 4096 gate rows
static constexpr int MROWS = (TT - 1) * BB; // 4064 valid rows
static constexpr int MPAD = 4096;
static constexpr int BH = BB * HH;          // 32768
static constexpr int NBLK = 256;            // recurrence grid

__device__ __forceinline__ unsigned short f2bf(float f) {
  unsigned int u = __float_as_uint(f);
  u = (u + 0x7FFFu + ((u >> 16) & 1u)) >> 16;
  return (unsigned short)u;
}
__device__ __forceinline__ float sigf(float x) { return 1.f / (1.f + __expf(-x)); }

__device__ __forceinline__ s16x8 pack8f(const float* p) {
  float4 x = *(const float4*)p;
  float4 y = *(const float4*)(p + 4);
  s16x8 r;
  r[0] = (short)f2bf(x.x); r[1] = (short)f2bf(x.y);
  r[2] = (short)f2bf(x.z); r[3] = (short)f2bf(x.w);
  r[4] = (short)f2bf(y.x); r[5] = (short)f2bf(y.y);
  r[6] = (short)f2bf(y.z); r[7] = (short)f2bf(y.w);
  return r;
}

__device__ __forceinline__ void gl_lds16(const void* g, void* l) {
  __builtin_amdgcn_global_load_lds(
      (const __attribute__((address_space(1))) unsigned int*)g,
      (__attribute__((address_space(3))) unsigned int*)l, 16, 0, 0);
}

__device__ __forceinline__ unsigned ldflag(const unsigned int* p) {
  return __hip_atomic_load(p, __ATOMIC_RELAXED, __HIP_MEMORY_SCOPE_AGENT);
}

// flags at 64B stride: flag i at [i*16]; pair (2l,2l+1) shares one 128B line.
#define FSTRIDE 16

// ---------------- zero / convert / embed ----------------

__global__ void zero2_k(uint4* __restrict__ p0, int n0, uint4* __restrict__ p1, int n1) {
  int i = blockIdx.x * blockDim.x + threadIdx.x;
  int stride = gridDim.x * blockDim.x;
  uint4 z = {0u, 0u, 0u, 0u};
  for (int k = i; k < n0; k += stride) p0[k] = z;
  for (int k = i; k < n1; k += stride) p1[k] = z;
}

__global__ void cvt2_k(const float4* __restrict__ a, u16x4* __restrict__ ao, int na4,
                       const float4* __restrict__ b, u16x4* __restrict__ bo, int nb4) {
  int i = blockIdx.x * blockDim.x + threadIdx.x;
  int stride = gridDim.x * blockDim.x;
  for (int k = i; k < na4; k += stride) {
    float4 v = a[k];
    u16x4 o;
    o[0] = f2bf(v.x); o[1] = f2bf(v.y); o[2] = f2bf(v.z); o[3] = f2bf(v.w);
    ao[k] = o;
  }
  for (int k = i; k < nb4; k += stride) {
    float4 v = b[k];
    u16x4 o;
    o[0] = f2bf(v.x); o[1] = f2bf(v.y); o[2] = f2bf(v.z); o[3] = f2bf(v.w);
    bo[k] = o;
  }
}

__global__ __launch_bounds__(256) void embed_k(const int* __restrict__ captions,
                                               const float* __restrict__ etab,
                                               const float* __restrict__ pos,
                                               unsigned short* __restrict__ X) {
  const int m = blockIdx.x;  // row = t*32 + b
  const int t = m >> 5, b = m & 31;
  if (t < TT - 1) {
    const int tok = captions[b * TT + t];
    const float* er = etab + (size_t)tok * EE;
    for (int e = threadIdx.x; e < EE; e += 256)
      X[(size_t)m * EE + e] = f2bf(er[e] + pos[e]);
  } else {
    for (int e = threadIdx.x; e < EE; e += 256) X[(size_t)m * EE + e] = 0;
  }
}

// ---------------- G0pre GEMM (C = A @ B^T + b0 + b1), swizzled staging -----

__global__ __launch_bounds__(256) void gemm_bt(const unsigned short* __restrict__ A,
                                               const unsigned short* __restrict__ Bm,
                                               int K, int N,
                                               const float* __restrict__ bias0,
                                               const float* __restrict__ bias1,
                                               float* __restrict__ Cout) {
  __shared__ unsigned short As[128 * 64];
  __shared__ unsigned short Bs[128 * 64];
  const int tid = threadIdx.x;
  const int lane = tid & 63, wave = tid >> 6;
  const int wm = wave & 1, wn = wave >> 1;
  const int m0 = blockIdx.x * 128, n0 = blockIdx.y * 128;
  const int sch = (((lane & 7) ^ ((lane >> 3) & 7)) * 8);  // swizzled source slot
  const int srbase = wave * 32 + (lane >> 3);
  f32x4 acc[4][4] = {};

  for (int k0 = 0; k0 < K; k0 += 64) {
    __syncthreads();
#pragma unroll
    for (int i = 0; i < 4; ++i) {
      const int r = srbase + i * 8;
      gl_lds16(&A[(size_t)(m0 + r) * K + k0 + sch], &As[(wave * 4 + i) * 512]);
      gl_lds16(&Bm[(size_t)(n0 + r) * K + k0 + sch], &Bs[(wave * 4 + i) * 512]);
    }
    __syncthreads();
#pragma unroll
    for (int kk = 0; kk < 64; kk += 32) {
      s16x8 af[4], bf[4];
#pragma unroll
      for (int f = 0; f < 4; ++f) {
        const int Ra = wm * 64 + f * 16 + (lane & 15);
        const int Rb = wn * 64 + f * 16 + (lane & 15);
        const int slot = (kk >> 3) + (lane >> 4);
        af[f] = *(const s16x8*)(&As[Ra * 64 + ((slot ^ (Ra & 7)) * 8)]);
        bf[f] = *(const s16x8*)(&Bs[Rb * 64 + ((slot ^ (Rb & 7)) * 8)]);
      }
#pragma unroll
      for (int mi = 0; mi < 4; ++mi)
#pragma unroll
        for (int ni = 0; ni < 4; ++ni)
          acc[mi][ni] = MFMA16(af[mi], bf[ni], acc[mi][ni]);
    }
  }

#pragma unroll
  for (int mi = 0; mi < 4; ++mi) {
#pragma unroll
    for (int ni = 0; ni < 4; ++ni) {
      const int col = n0 + wn * 64 + ni * 16 + (lane & 15);
      float bs = bias0[col] + bias1[col];
      const int mbase = m0 + wm * 64 + mi * 16 + (lane >> 4) * 4;
#pragma unroll
      for (int r = 0; r < 4; ++r) {
        int m = mbase + r;
        if (m < MROWS) Cout[(size_t)m * N + col] = acc[mi][ni][r] + bs;
      }
    }
  }
}

// ---------------- projection GEMM: T4 counted-vmcnt + T2 swizzle + T5 ------
// j==0 blocks also zero out[:,0,:] (fused epilogue; replaces zero_out_t0).

__global__ __launch_bounds__(512, 1) void proj_gemm(const unsigned short* __restrict__ hsA,
                                                    const unsigned short* __restrict__ Woutb,
                                                    const float* __restrict__ bout,
                                                    float* __restrict__ out) {
  __shared__ unsigned short As[2][256 * 64];  // 64KB
  __shared__ unsigned short Bs[2][256 * 64];  // 64KB
  const int tid = threadIdx.x;
  const int lane = tid & 63, wave = tid >> 6;    // 8 waves
  const int wm = wave & 1, wn = wave >> 1;       // wm 0..1, wn 0..3
  const int T = blockIdx.x;
  const int bq = T & 15;
  const int j = 2 * (bq & 7) + (bq >> 3);        // XCD-pinned m-stripe pair
  const int n = T >> 4;                          // 0..124
  const int m0 = j * 256, n0 = n * 256;
  const int sch = (((lane & 7) ^ ((lane >> 3) & 7)) * 8);  // swizzled source slot
  const int rbase = tid >> 3;                    // staging row (this thread)
  f32x4 acc[8][4] = {};

  auto stageP = [&](int ks, int buf) {
    const int k0 = ks * 64;
#pragma unroll
    for (int i = 0; i < 4; ++i) {
      const int r = rbase + i * 64;  // rows 0..255 over 4 issues
      gl_lds16(&hsA[(size_t)(m0 + r) * HH + k0 + sch], &As[buf][(wave * 64 + i * 512) * 8]);
      gl_lds16(&Woutb[(size_t)(n0 + r) * HH + k0 + sch], &Bs[buf][(wave * 64 + i * 512) * 8]);
    }
  };

  // prologue: stage K-step 0 into buf 0 (8 loads/wave outstanding)
  stageP(0, 0);

  for (int ks = 0; ks < 16; ++ks) {
    const int cur = ks & 1;
    if (ks < 15) {
      stageP(ks + 1, cur ^ 1);                      // +8 -> 16 outstanding
      asm volatile("s_waitcnt vmcnt(8)" ::: "memory");  // stage(ks) landed
    } else {
      asm volatile("s_waitcnt vmcnt(0)" ::: "memory");  // final drain
    }
    __builtin_amdgcn_s_barrier();  // all waves' stage(ks) complete
    __builtin_amdgcn_s_setprio(1);
#pragma unroll
    for (int kk = 0; kk < 64; kk += 32) {
      s16x8 af[8], bf[4];
#pragma unroll
      for (int f = 0; f < 8; ++f) {
        const int Ra = wm * 128 + f * 16 + (lane & 15);
        const int slot = (kk >> 3) + (lane >> 4);
        af[f] = *(const s16x8*)(&As[cur][Ra * 64 + ((slot ^ (Ra & 7)) * 8)]);
      }
#pragma unroll
      for (int f = 0; f < 4; ++f) {
        const int Rb = wn * 64 + f * 16 + (lane & 15);
        const int slot = (kk >> 3) + (lane >> 4);
        bf[f] = *(const s16x8*)(&Bs[cur][Rb * 64 + ((slot ^ (Rb & 7)) * 8)]);
      }
#pragma unroll
      for (int mi = 0; mi < 8; ++mi)
#pragma unroll
        for (int ni = 0; ni < 4; ++ni)
          acc[mi][ni] = MFMA16(af[mi], bf[ni], acc[mi][ni]);
    }
    __builtin_amdgcn_s_setprio(0);
    asm volatile("" ::: "memory");
    __builtin_amdgcn_s_barrier();  // reads of buf done before its next overwrite
  }

#pragma unroll
  for (int mi = 0; mi < 8; ++mi) {
#pragma unroll
    for (int ni = 0; ni < 4; ++ni) {
      const int col = n0 + wn * 64 + ni * 16 + (lane & 15);
      const float bs = bout[col];
      const int mbase = m0 + wm * 128 + mi * 16 + (lane >> 4) * 4;
#pragma unroll
      for (int r2 = 0; r2 < 4; ++r2) {
        const int m = mbase + r2;
        if (m < MROWS) {
          const int tt = m >> 5, b2 = m & 31;
          out[((size_t)b2 * TT + tt + 1) * VV + col] = acc[mi][ni][r2] + bs;
        }
      }
    }
  }

  // fused: out[:, 0, n-slice] = 0 (j==0 blocks exactly tile 32 x 32000)
  if (j == 0) {
    for (int i = tid; i < 32 * 256; i += 512) {
      const int b2 = i >> 8, c = i & 255;
      out[(size_t)b2 * TT * VV + n0 + c] = 0.f;
    }
  }
}

// ---------------- persistent 2-layer LSTM, flat direct-poll barriers ------
// Poll-storm mitigation: flags packed to 64B stride (2/line) + backoff polls
// (first miss sleep(20)~0.55us, then sleep(5)~0.13us granularity).

__global__ __launch_bounds__(256, 1) void lstm_persist(
    const float* __restrict__ Whh0f, const float* __restrict__ Wih1f,
    const float* __restrict__ Whh1f, const float* __restrict__ G0pre,
    const float* __restrict__ bih1, const float* __restrict__ bhh1,
    unsigned short* __restrict__ h0seq, unsigned short* __restrict__ hseq1,
    unsigned short* __restrict__ hs_all,
    unsigned int* __restrict__ flags0, unsigned int* __restrict__ flags1) {
  __shared__ float parts[4][2][2][16][16];  // 8KB
  const int bid = blockIdx.x;
  const int layer = bid >> 7;
  const int blk = bid & 127;
  const int tid = threadIdx.x, lane = tid & 63, wave = tid >> 6;
  const int jb = blk * 8;
  const int colIdx = lane & 15;
  const int kq = lane >> 4;
  const int wrow0 = (colIdx >> 3) * HH + jb + (colIdx & 7);

  const int cb = tid >> 3, cjj = tid & 7;
  float creg = 0.f;
  float bsum[4];
  if (layer == 1) {
#pragma unroll
    for (int gi = 0; gi < 4; ++gi)
      bsum[gi] = bih1[gi * HH + jb + cjj] + bhh1[gi * HH + jb + cjj];
  }

  // ---- recurrent weights into registers (fp32 -> bf16) ----
  s16x8 wreg[16][2];
  const int kb = (layer == 0) ? wave * 256 : (wave & 1) * 512;
  if (layer == 0) {
#pragma unroll
    for (int fi = 0; fi < 2; ++fi) {
      const float* wp = Whh0f + (size_t)(wrow0 + fi * 2 * HH) * HH + kb + kq * 8;
#pragma unroll
      for (int ks = 0; ks < 8; ++ks) wreg[ks][fi] = pack8f(wp + ks * 32);
    }
  } else {
    const float* Wsrc = (wave < 2) ? Wih1f : Whh1f;
#pragma unroll
    for (int fi = 0; fi < 2; ++fi) {
      const float* wp = Wsrc + (size_t)(wrow0 + fi * 2 * HH) * HH + kb + kq * 8;
#pragma unroll
      for (int ks = 0; ks < 16; ++ks) wreg[ks][fi] = pack8f(wp + ks * 32);
    }
  }

  const int frag_off = (kb >> 3) * 256 + kq * 256 + (lane & 15) * 8;

  if (layer == 0) {
    // =================== L0 chain ===================
    for (int t = 0; t < TT - 1; ++t) {
      float gpre[4];
#pragma unroll
      for (int gi = 0; gi < 4; ++gi)
        gpre[gi] = G0pre[((size_t)t * BB + cb) * FH + gi * HH + jb + cjj];

      if (t > 0 && wave == 0) {
        const unsigned tgt = (unsigned)t;
        unsigned a = ldflag(&flags0[(lane * 2 + 0) * FSTRIDE]);
        unsigned b = ldflag(&flags0[(lane * 2 + 1) * FSTRIDE]);
        if (!__all(min(a, b) >= tgt)) {
          __builtin_amdgcn_s_sleep(20);
          for (;;) {
            a = ldflag(&flags0[(lane * 2 + 0) * FSTRIDE]);
            b = ldflag(&flags0[(lane * 2 + 1) * FSTRIDE]);
            if (__all(min(a, b) >= tgt)) break;
            __builtin_amdgcn_s_sleep(5);
          }
        }
      }
      __syncthreads();
      asm volatile("" ::: "memory");

      const unsigned short* a0 = h0seq + (size_t)t * BH + frag_off;
      const unsigned short* a1 = a0 + 128;
      f32x4 acc00 = {}, acc01 = {}, acc10 = {}, acc11 = {};
#pragma unroll
      for (int ks = 0; ks < 8; ++ks) {
        s16x8 av0 = *(const s16x8*)(a0 + ks * 1024);
        s16x8 av1 = *(const s16x8*)(a1 + ks * 1024);
        acc00 = MFMA16(av0, wreg[ks][0], acc00);
        acc01 = MFMA16(av0, wreg[ks][1], acc01);
        acc10 = MFMA16(av1, wreg[ks][0], acc10);
        acc11 = MFMA16(av1, wreg[ks][1], acc11);
      }
#pragma unroll
      for (int r = 0; r < 4; ++r) {
        parts[wave][0][0][kq * 4 + r][colIdx] = acc00[r];
        parts[wave][0][1][kq * 4 + r][colIdx] = acc01[r];
        parts[wave][1][0][kq * 4 + r][colIdx] = acc10[r];
        parts[wave][1][1][kq * 4 + r][colIdx] = acc11[r];
      }
      __syncthreads();
      float g[4];
#pragma unroll
      for (int gi = 0; gi < 4; ++gi) {
        float s = gpre[gi];
        const int fi = gi >> 1, c = (gi & 1) * 8 + cjj;
#pragma unroll
        for (int w4 = 0; w4 < 4; ++w4) s += parts[w4][cb >> 4][fi][cb & 15][c];
        g[gi] = s;
      }
      const float i_ = sigf(g[0]), f_ = sigf(g[1]), gg = tanhf(g[2]), o_ = sigf(g[3]);
      creg = f_ * creg + i_ * gg;
      *(volatile unsigned short*)&h0seq[(size_t)(t + 1) * BH + blk * 256 + tid] =
          f2bf(o_ * tanhf(creg));

      asm volatile("s_waitcnt vmcnt(0)" ::: "memory");
      __syncthreads();
      if (tid == 0) *(volatile unsigned int*)&flags0[blk * FSTRIDE] = (unsigned)(t + 1);
    }
  } else {
    // =================== L1 chain ===================
    for (int t = 1; t < TT; ++t) {
      if (wave == 0) {
        const unsigned t0 = (unsigned)t, t1 = (unsigned)(t - 1);
        unsigned a0 = ldflag(&flags0[(lane * 2 + 0) * FSTRIDE]);
        unsigned b0 = ldflag(&flags0[(lane * 2 + 1) * FSTRIDE]);
        unsigned a1 = ldflag(&flags1[(lane * 2 + 0) * FSTRIDE]);
        unsigned b1 = ldflag(&flags1[(lane * 2 + 1) * FSTRIDE]);
        bool ok = (min(a0, b0) >= t0) && (min(a1, b1) >= t1);
        if (!__all(ok)) {
          __builtin_amdgcn_s_sleep(20);
          for (;;) {
            a0 = ldflag(&flags0[(lane * 2 + 0) * FSTRIDE]);
            b0 = ldflag(&flags0[(lane * 2 + 1) * FSTRIDE]);
            a1 = ldflag(&flags1[(lane * 2 + 0) * FSTRIDE]);
            b1 = ldflag(&flags1[(lane * 2 + 1) * FSTRIDE]);
            ok = (min(a0, b0) >= t0) && (min(a1, b1) >= t1);
            if (__all(ok)) break;
            __builtin_amdgcn_s_sleep(5);
          }
        }
      }
      __syncthreads();
      asm volatile("" ::: "memory");

      const unsigned short* base = (wave < 2)
                                       ? (h0seq + (size_t)t * BH)         // h0(t-1)
                                       : (hseq1 + (size_t)(t - 1) * BH);  // h1(t-2)
      const unsigned short* a0 = base + frag_off;
      const unsigned short* a1 = a0 + 128;
      f32x4 acc00 = {}, acc01 = {}, acc10 = {}, acc11 = {};
#pragma unroll
      for (int ks = 0; ks < 16; ++ks) {
        s16x8 av0 = *(const s16x8*)(a0 + ks * 1024);
        s16x8 av1 = *(const s16x8*)(a1 + ks * 1024);
        acc00 = MFMA16(av0, wreg[ks][0], acc00);
        acc01 = MFMA16(av0, wreg[ks][1], acc01);
        acc10 = MFMA16(av1, wreg[ks][0], acc10);
        acc11 = MFMA16(av1, wreg[ks][1], acc11);
      }
#pragma unroll
      for (int r = 0; r < 4; ++r) {
        parts[wave][0][0][kq * 4 + r][colIdx] = acc00[r];
        parts[wave][0][1][kq * 4 + r][colIdx] = acc01[r];
        parts[wave][1][0][kq * 4 + r][colIdx] = acc10[r];
        parts[wave][1][1][kq * 4 + r][colIdx] = acc11[r];
      }
      __syncthreads();
      float g[4];
#pragma unroll
      for (int gi = 0; gi < 4; ++gi) {
        float s = bsum[gi];
        const int fi = gi >> 1, c = (gi & 1) * 8 + cjj;
#pragma unroll
        for (int w4 = 0; w4 < 4; ++w4) s += parts[w4][cb >> 4][fi][cb & 15][c];
        g[gi] = s;
      }
      const float i_ = sigf(g[0]), f_ = sigf(g[1]), gg = tanhf(g[2]), o_ = sigf(g[3]);
      creg = f_ * creg + i_ * gg;
      const unsigned short hv = f2bf(o_ * tanhf(creg));
      *(volatile unsigned short*)&hseq1[(size_t)t * BH + blk * 256 + tid] = hv;
      hs_all[(size_t)t * BH + (size_t)cb * HH + jb + cjj] = hv;  // plain (GEMM copy)

      asm volatile("s_waitcnt vmcnt(0)" ::: "memory");
      __syncthreads();
      if (tid == 0) *(volatile unsigned int*)&flags1[blk * FSTRIDE] = (unsigned)t;
    }
  }
}

// ---------------- host ----------------

extern "C" void kernel_launch(void* const* d_in, const int* in_sizes, int n_in,
                              void* d_out, int out_size, void* d_ws, size_t ws_size,
                              hipStream_t stream) {
  const int* captions = (const int*)d_in[1];
  const float* etab = (const float*)d_in[2];
  const float* pos = (const float*)d_in[3];
  const float* Wih0 = (const float*)d_in[4];
  const float* Whh0 = (const float*)d_in[5];
  const float* bih0 = (const float*)d_in[6];
  const float* bhh0 = (const float*)d_in[7];
  const float* Wih1 = (const float*)d_in[8];
  const float* Whh1 = (const float*)d_in[9];
  const float* bih1 = (const float*)d_in[10];
  const float* bhh1 = (const float*)d_in[11];
  const float* Wout = (const float*)d_in[12];
  const float* bout = (const float*)d_in[13];
  float* out = (float*)d_out;

  char* w = (char*)d_ws;
  auto alloc = [&](size_t bytes) {
    char* p = w;
    w += (bytes + 255) & ~(size_t)255;
    return p;
  };
  // layout: flags0(8KB) flags1(8KB) h0seq hseq1 hs_all ...
  unsigned int* flags0 = (unsigned int*)alloc(128 * 64);
  unsigned int* flags1 = (unsigned int*)alloc(128 * 64);
  unsigned short* h0seq = (unsigned short*)alloc((size_t)TT * BH * 2);   // block-major
  unsigned short* hseq1 = (unsigned short*)alloc((size_t)TT * BH * 2);   // block-major
  unsigned short* hs_all = (unsigned short*)alloc((size_t)4160 * HH * 2);// row-major

  unsigned short* Xb = (unsigned short*)alloc((size_t)MPAD * EE * 2);
  unsigned short* Wih0b = (unsigned short*)alloc((size_t)FH * EE * 2);
  unsigned short* Woutb = (unsigned short*)alloc((size_t)VV * HH * 2);
  float* G0pre = (float*)alloc((size_t)MROWS * FH * 4);

  // 1) zero read-before-write state: [flags0|flags1|h0seq slot0] and hseq1 slot0
  hipLaunchKernelGGL(zero2_k, dim3(40), dim3(256), 0, stream,
                     (uint4*)flags0, (int)((128 * 64 * 2 + BH * 2) / 16),
                     (uint4*)hseq1, (int)((BH * 2) / 16));
  // 2) convert Wih0 + Wout to bf16 (one kernel)
  hipLaunchKernelGGL(cvt2_k, dim3(4096), dim3(256), 0, stream,
                     (const float4*)Wih0, (u16x4*)Wih0b, FH * EE / 4,
                     (const float4*)Wout, (u16x4*)Woutb, VV * HH / 4);
  // 3) embeddings + pos -> X
  hipLaunchKernelGGL(embed_k, dim3(MPAD), dim3(256), 0, stream, captions, etab, pos, Xb);
  // 4) G0pre = X @ Wih0^T + bih0 + bhh0
  hipLaunchKernelGGL(gemm_bt, dim3(32, 32), dim3(256), 0, stream, Xb, Wih0b, EE, FH, bih0,
                     bhh0, G0pre);
  // 5) persistent recurrence (packed flags + backoff polls)
  hipLaunchKernelGGL(lstm_persist, dim3(NBLK), dim3(256), 0, stream, Whh0, Wih1, Whh1, G0pre,
                     bih1, bhh1, h0seq, hseq1, hs_all, flags0, flags1);
  // 6) projection (T4+T2+T5, fused t0-zero)
  hipLaunchKernelGGL(proj_gemm, dim3(2000), dim3(512), 0, stream, hs_all + (size_t)BH,
                     Woutb, bout, out);
}

// Round 18
// 1243.710 us; speedup vs baseline: 1.0331x; 1.0331x over previous
//
#include <hip/hip_runtime.h>
#include <hip/hip_bf16.h>
#include <math.h>

typedef __attribute__((ext_vector_type(4))) float f32x4;
typedef __attribute__((ext_vector_type(8))) short s16x8;
typedef __attribute__((ext_vector_type(4))) unsigned short u16x4;

#define MFMA16(a, b, c) __builtin_amdgcn_mfma_f32_16x16x32_bf16(a, b, c, 0, 0, 0)

static constexpr int BB = 32, TT = 128, EE = 512, HH = 1024, VV = 32000;
static constexpr int FH = 4 * HH;           // 4096 gate rows
static constexpr int MROWS = (TT - 1) * BB; // 4064 valid rows
static constexpr int BH = BB * HH;          // 32768
static constexpr int BE = BB * EE;          // 16384
static constexpr int NBLK = 256;            // recurrence grid

__device__ __forceinline__ unsigned short f2bf(float f) {
  unsigned int u = __float_as_uint(f);
  u = (u + 0x7FFFu + ((u >> 16) & 1u)) >> 16;
  return (unsigned short)u;
}
__device__ __forceinline__ float sigf(float x) { return 1.f / (1.f + __expf(-x)); }

__device__ __forceinline__ s16x8 pack8f(const float* p) {
  float4 x = *(const float4*)p;
  float4 y = *(const float4*)(p + 4);
  s16x8 r;
  r[0] = (short)f2bf(x.x); r[1] = (short)f2bf(x.y);
  r[2] = (short)f2bf(x.z); r[3] = (short)f2bf(x.w);
  r[4] = (short)f2bf(y.x); r[5] = (short)f2bf(y.y);
  r[6] = (short)f2bf(y.z); r[7] = (short)f2bf(y.w);
  return r;
}

__device__ __forceinline__ void gl_lds16(const void* g, void* l) {
  __builtin_amdgcn_global_load_lds(
      (const __attribute__((address_space(1))) unsigned int*)g,
      (__attribute__((address_space(3))) unsigned int*)l, 16, 0, 0);
}

__device__ __forceinline__ unsigned ldflag(const unsigned int* p) {
  return __hip_atomic_load(p, __ATOMIC_RELAXED, __HIP_MEMORY_SCOPE_AGENT);
}

#define FSTRIDE 32  // one 128B line per flag (round-16 measured best)

// ---------------- zero / convert / embed ----------------

__global__ void zero2_k(uint4* __restrict__ p0, int n0, uint4* __restrict__ p1, int n1) {
  int i = blockIdx.x * blockDim.x + threadIdx.x;
  int stride = gridDim.x * blockDim.x;
  uint4 z = {0u, 0u, 0u, 0u};
  for (int k = i; k < n0; k += stride) p0[k] = z;
  for (int k = i; k < n1; k += stride) p1[k] = z;
}

__global__ void cvt1_k(const float4* __restrict__ a, u16x4* __restrict__ ao, int na4) {
  int i = blockIdx.x * blockDim.x + threadIdx.x;
  int stride = gridDim.x * blockDim.x;
  for (int k = i; k < na4; k += stride) {
    float4 v = a[k];
    u16x4 o;
    o[0] = f2bf(v.x); o[1] = f2bf(v.y); o[2] = f2bf(v.z); o[3] = f2bf(v.w);
    ao[k] = o;
  }
}

// Embeddings in block-major record layout: X[t][e>>3][b][e&7]
__global__ __launch_bounds__(256) void embed_k(const int* __restrict__ captions,
                                               const float* __restrict__ etab,
                                               const float* __restrict__ pos,
                                               unsigned short* __restrict__ Xseq) {
  const int m = blockIdx.x;  // 0..4063 : t*32 + b, t < 127
  const int t = m >> 5, b = m & 31;
  const int tok = captions[b * TT + t];
  const float* er = etab + (size_t)tok * EE;
  unsigned short* xt = Xseq + (size_t)t * BE;
  for (int e = threadIdx.x; e < EE; e += 256)
    xt[(e >> 3) * 256 + b * 8 + (e & 7)] = f2bf(er[e] + pos[e]);
}

// ---------------- projection GEMM: T4 counted-vmcnt + T2 swizzle + T5 ------
// j==0 blocks also zero out[:,0,:] (fused epilogue).

__global__ __launch_bounds__(512, 1) void proj_gemm(const unsigned short* __restrict__ hsA,
                                                    const unsigned short* __restrict__ Woutb,
                                                    const float* __restrict__ bout,
                                                    float* __restrict__ out) {
  __shared__ unsigned short As[2][256 * 64];  // 64KB
  __shared__ unsigned short Bs[2][256 * 64];  // 64KB
  const int tid = threadIdx.x;
  const int lane = tid & 63, wave = tid >> 6;    // 8 waves
  const int wm = wave & 1, wn = wave >> 1;       // wm 0..1, wn 0..3
  const int T = blockIdx.x;
  const int bq = T & 15;
  const int j = 2 * (bq & 7) + (bq >> 3);        // XCD-pinned m-stripe pair
  const int n = T >> 4;                          // 0..124
  const int m0 = j * 256, n0 = n * 256;
  const int sch = (((lane & 7) ^ ((lane >> 3) & 7)) * 8);  // swizzled source slot
  const int rbase = tid >> 3;                    // staging row (this thread)
  f32x4 acc[8][4] = {};

  auto stageP = [&](int ks, int buf) {
    const int k0 = ks * 64;
#pragma unroll
    for (int i = 0; i < 4; ++i) {
      const int r = rbase + i * 64;
      gl_lds16(&hsA[(size_t)(m0 + r) * HH + k0 + sch], &As[buf][(wave * 64 + i * 512) * 8]);
      gl_lds16(&Woutb[(size_t)(n0 + r) * HH + k0 + sch], &Bs[buf][(wave * 64 + i * 512) * 8]);
    }
  };

  stageP(0, 0);

  for (int ks = 0; ks < 16; ++ks) {
    const int cur = ks & 1;
    if (ks < 15) {
      stageP(ks + 1, cur ^ 1);
      asm volatile("s_waitcnt vmcnt(8)" ::: "memory");
    } else {
      asm volatile("s_waitcnt vmcnt(0)" ::: "memory");
    }
    __builtin_amdgcn_s_barrier();
    __builtin_amdgcn_s_setprio(1);
#pragma unroll
    for (int kk = 0; kk < 64; kk += 32) {
      s16x8 af[8], bf[4];
#pragma unroll
      for (int f = 0; f < 8; ++f) {
        const int Ra = wm * 128 + f * 16 + (lane & 15);
        const int slot = (kk >> 3) + (lane >> 4);
        af[f] = *(const s16x8*)(&As[cur][Ra * 64 + ((slot ^ (Ra & 7)) * 8)]);
      }
#pragma unroll
      for (int f = 0; f < 4; ++f) {
        const int Rb = wn * 64 + f * 16 + (lane & 15);
        const int slot = (kk >> 3) + (lane >> 4);
        bf[f] = *(const s16x8*)(&Bs[cur][Rb * 64 + ((slot ^ (Rb & 7)) * 8)]);
      }
#pragma unroll
      for (int mi = 0; mi < 8; ++mi)
#pragma unroll
        for (int ni = 0; ni < 4; ++ni)
          acc[mi][ni] = MFMA16(af[mi], bf[ni], acc[mi][ni]);
    }
    __builtin_amdgcn_s_setprio(0);
    asm volatile("" ::: "memory");
    __builtin_amdgcn_s_barrier();
  }

#pragma unroll
  for (int mi = 0; mi < 8; ++mi) {
#pragma unroll
    for (int ni = 0; ni < 4; ++ni) {
      const int col = n0 + wn * 64 + ni * 16 + (lane & 15);
      const float bs = bout[col];
      const int mbase = m0 + wm * 128 + mi * 16 + (lane >> 4) * 4;
#pragma unroll
      for (int r2 = 0; r2 < 4; ++r2) {
        const int m = mbase + r2;
        if (m < MROWS) {
          const int tt = m >> 5, b2 = m & 31;
          out[((size_t)b2 * TT + tt + 1) * VV + col] = acc[mi][ni][r2] + bs;
        }
      }
    }
  }

  if (j == 0) {
    for (int i = tid; i < 32 * 256; i += 512) {
      const int b2 = i >> 8, c = i & 255;
      out[(size_t)b2 * TT * VV + n0 + c] = 0.f;
    }
  }
}

// ---------------- persistent 2-layer LSTM, fused X-side (no G0pre) --------
// Round-16 barrier structure exactly (128B-stride flags, wave-0 poll,
// sleep(1)). L0 gates = X(t)@Wih0^T + h0(t)@Whh0^T + bih0 + bhh0, with
// Wih0 fragments ALSO register-resident (K=512 split over 4 waves).

__global__ __launch_bounds__(256, 1) void lstm_persist(
    const float* __restrict__ Whh0f, const float* __restrict__ Wih0f,
    const float* __restrict__ Wih1f, const float* __restrict__ Whh1f,
    const float* __restrict__ bih0, const float* __restrict__ bhh0,
    const float* __restrict__ bih1, const float* __restrict__ bhh1,
    const unsigned short* __restrict__ Xseq,
    unsigned short* __restrict__ h0seq, unsigned short* __restrict__ hseq1,
    unsigned short* __restrict__ hs_all,
    unsigned int* __restrict__ flags0, unsigned int* __restrict__ flags1) {
  __shared__ float parts[4][2][2][16][16];  // 8KB
  const int bid = blockIdx.x;
  const int layer = bid >> 7;
  const int blk = bid & 127;
  const int tid = threadIdx.x, lane = tid & 63, wave = tid >> 6;
  const int jb = blk * 8;
  const int colIdx = lane & 15;
  const int kq = lane >> 4;
  const int wrow0 = (colIdx >> 3) * HH + jb + (colIdx & 7);

  const int cb = tid >> 3, cjj = tid & 7;
  float creg = 0.f;
  float bsum[4];
  if (layer == 0) {
#pragma unroll
    for (int gi = 0; gi < 4; ++gi)
      bsum[gi] = bih0[gi * HH + jb + cjj] + bhh0[gi * HH + jb + cjj];
  } else {
#pragma unroll
    for (int gi = 0; gi < 4; ++gi)
      bsum[gi] = bih1[gi * HH + jb + cjj] + bhh1[gi * HH + jb + cjj];
  }

  // ---- recurrent weights into registers (fp32 -> bf16) ----
  s16x8 wreg[16][2];   // h-side
  s16x8 wregx[4][2];   // X-side (L0 only, K=512)
  const int kb = (layer == 0) ? wave * 256 : (wave & 1) * 512;
  const int kbx = wave * 128;
  if (layer == 0) {
#pragma unroll
    for (int fi = 0; fi < 2; ++fi) {
      const float* wp = Whh0f + (size_t)(wrow0 + fi * 2 * HH) * HH + kb + kq * 8;
#pragma unroll
      for (int ks = 0; ks < 8; ++ks) wreg[ks][fi] = pack8f(wp + ks * 32);
      const float* wpx = Wih0f + (size_t)(wrow0 + fi * 2 * HH) * EE + kbx + kq * 8;
#pragma unroll
      for (int ks = 0; ks < 4; ++ks) wregx[ks][fi] = pack8f(wpx + ks * 32);
    }
  } else {
    const float* Wsrc = (wave < 2) ? Wih1f : Whh1f;
#pragma unroll
    for (int fi = 0; fi < 2; ++fi) {
      const float* wp = Wsrc + (size_t)(wrow0 + fi * 2 * HH) * HH + kb + kq * 8;
#pragma unroll
      for (int ks = 0; ks < 16; ++ks) wreg[ks][fi] = pack8f(wp + ks * 32);
    }
  }

  const int frag_off = (kb >> 3) * 256 + kq * 256 + (lane & 15) * 8;
  const int frag_offX = (wave * 16 + kq) * 256 + (lane & 15) * 8;

  if (layer == 0) {
    // =================== L0 chain ===================
    for (int t = 0; t < TT - 1; ++t) {
      if (t > 0 && wave == 0) {
        const unsigned tgt = (unsigned)t;
        for (;;) {
          unsigned a = ldflag(&flags0[(lane * 2 + 0) * FSTRIDE]);
          unsigned b = ldflag(&flags0[(lane * 2 + 1) * FSTRIDE]);
          if (__all(min(a, b) >= tgt)) break;
          __builtin_amdgcn_s_sleep(1);
        }
      }
      __syncthreads();
      asm volatile("" ::: "memory");

      const unsigned short* x0 = Xseq + (size_t)t * BE + frag_offX;
      const unsigned short* x1 = x0 + 128;
      const unsigned short* a0 = h0seq + (size_t)t * BH + frag_off;
      const unsigned short* a1 = a0 + 128;
      f32x4 acc00 = {}, acc01 = {}, acc10 = {}, acc11 = {};
#pragma unroll
      for (int ks = 0; ks < 4; ++ks) {
        s16x8 xv0 = *(const s16x8*)(x0 + ks * 1024);
        s16x8 xv1 = *(const s16x8*)(x1 + ks * 1024);
        acc00 = MFMA16(xv0, wregx[ks][0], acc00);
        acc01 = MFMA16(xv0, wregx[ks][1], acc01);
        acc10 = MFMA16(xv1, wregx[ks][0], acc10);
        acc11 = MFMA16(xv1, wregx[ks][1], acc11);
      }
#pragma unroll
      for (int ks = 0; ks < 8; ++ks) {
        s16x8 av0 = *(const s16x8*)(a0 + ks * 1024);
        s16x8 av1 = *(const s16x8*)(a1 + ks * 1024);
        acc00 = MFMA16(av0, wreg[ks][0], acc00);
        acc01 = MFMA16(av0, wreg[ks][1], acc01);
        acc10 = MFMA16(av1, wreg[ks][0], acc10);
        acc11 = MFMA16(av1, wreg[ks][1], acc11);
      }
#pragma unroll
      for (int r = 0; r < 4; ++r) {
        parts[wave][0][0][kq * 4 + r][colIdx] = acc00[r];
        parts[wave][0][1][kq * 4 + r][colIdx] = acc01[r];
        parts[wave][1][0][kq * 4 + r][colIdx] = acc10[r];
        parts[wave][1][1][kq * 4 + r][colIdx] = acc11[r];
      }
      __syncthreads();
      float g[4];
#pragma unroll
      for (int gi = 0; gi < 4; ++gi) {
        float s = bsum[gi];
        const int fi = gi >> 1, c = (gi & 1) * 8 + cjj;
#pragma unroll
        for (int w4 = 0; w4 < 4; ++w4) s += parts[w4][cb >> 4][fi][cb & 15][c];
        g[gi] = s;
      }
      const float i_ = sigf(g[0]), f_ = sigf(g[1]), gg = tanhf(g[2]), o_ = sigf(g[3]);
      creg = f_ * creg + i_ * gg;
      *(volatile unsigned short*)&h0seq[(size_t)(t + 1) * BH + blk * 256 + tid] =
          f2bf(o_ * tanhf(creg));

      asm volatile("s_waitcnt vmcnt(0)" ::: "memory");
      __syncthreads();
      if (tid == 0) *(volatile unsigned int*)&flags0[blk * FSTRIDE] = (unsigned)(t + 1);
    }
  } else {
    // =================== L1 chain ===================
    for (int t = 1; t < TT; ++t) {
      if (wave == 0) {
        const unsigned t0 = (unsigned)t, t1 = (unsigned)(t - 1);
        for (;;) {
          unsigned a0f = ldflag(&flags0[(lane * 2 + 0) * FSTRIDE]);
          unsigned b0f = ldflag(&flags0[(lane * 2 + 1) * FSTRIDE]);
          unsigned a1f = ldflag(&flags1[(lane * 2 + 0) * FSTRIDE]);
          unsigned b1f = ldflag(&flags1[(lane * 2 + 1) * FSTRIDE]);
          bool ok = (min(a0f, b0f) >= t0) && (min(a1f, b1f) >= t1);
          if (__all(ok)) break;
          __builtin_amdgcn_s_sleep(1);
        }
      }
      __syncthreads();
      asm volatile("" ::: "memory");

      const unsigned short* base = (wave < 2)
                                       ? (h0seq + (size_t)t * BH)         // h0(t-1)
                                       : (hseq1 + (size_t)(t - 1) * BH);  // h1(t-2)
      const unsigned short* a0 = base + frag_off;
      const unsigned short* a1 = a0 + 128;
      f32x4 acc00 = {}, acc01 = {}, acc10 = {}, acc11 = {};
#pragma unroll
      for (int ks = 0; ks < 16; ++ks) {
        s16x8 av0 = *(const s16x8*)(a0 + ks * 1024);
        s16x8 av1 = *(const s16x8*)(a1 + ks * 1024);
        acc00 = MFMA16(av0, wreg[ks][0], acc00);
        acc01 = MFMA16(av0, wreg[ks][1], acc01);
        acc10 = MFMA16(av1, wreg[ks][0], acc10);
        acc11 = MFMA16(av1, wreg[ks][1], acc11);
      }
#pragma unroll
      for (int r = 0; r < 4; ++r) {
        parts[wave][0][0][kq * 4 + r][colIdx] = acc00[r];
        parts[wave][0][1][kq * 4 + r][colIdx] = acc01[r];
        parts[wave][1][0][kq * 4 + r][colIdx] = acc10[r];
        parts[wave][1][1][kq * 4 + r][colIdx] = acc11[r];
      }
      __syncthreads();
      float g[4];
#pragma unroll
      for (int gi = 0; gi < 4; ++gi) {
        float s = bsum[gi];
        const int fi = gi >> 1, c = (gi & 1) * 8 + cjj;
#pragma unroll
        for (int w4 = 0; w4 < 4; ++w4) s += parts[w4][cb >> 4][fi][cb & 15][c];
        g[gi] = s;
      }
      const float i_ = sigf(g[0]), f_ = sigf(g[1]), gg = tanhf(g[2]), o_ = sigf(g[3]);
      creg = f_ * creg + i_ * gg;
      const unsigned short hv = f2bf(o_ * tanhf(creg));
      *(volatile unsigned short*)&hseq1[(size_t)t * BH + blk * 256 + tid] = hv;
      hs_all[(size_t)t * BH + (size_t)cb * HH + jb + cjj] = hv;  // plain (GEMM copy)

      asm volatile("s_waitcnt vmcnt(0)" ::: "memory");
      __syncthreads();
      if (tid == 0) *(volatile unsigned int*)&flags1[blk * FSTRIDE] = (unsigned)t;
    }
  }
}

// ---------------- host ----------------

extern "C" void kernel_launch(void* const* d_in, const int* in_sizes, int n_in,
                              void* d_out, int out_size, void* d_ws, size_t ws_size,
                              hipStream_t stream) {
  const int* captions = (const int*)d_in[1];
  const float* etab = (const float*)d_in[2];
  const float* pos = (const float*)d_in[3];
  const float* Wih0 = (const float*)d_in[4];
  const float* Whh0 = (const float*)d_in[5];
  const float* bih0 = (const float*)d_in[6];
  const float* bhh0 = (const float*)d_in[7];
  const float* Wih1 = (const float*)d_in[8];
  const float* Whh1 = (const float*)d_in[9];
  const float* bih1 = (const float*)d_in[10];
  const float* bhh1 = (const float*)d_in[11];
  const float* Wout = (const float*)d_in[12];
  const float* bout = (const float*)d_in[13];
  float* out = (float*)d_out;

  char* w = (char*)d_ws;
  auto alloc = [&](size_t bytes) {
    char* p = w;
    w += (bytes + 255) & ~(size_t)255;
    return p;
  };
  // layout: flags0(16KB) flags1(16KB) h0seq hseq1 hs_all Xseq Woutb
  unsigned int* flags0 = (unsigned int*)alloc(128 * 128);
  unsigned int* flags1 = (unsigned int*)alloc(128 * 128);
  unsigned short* h0seq = (unsigned short*)alloc((size_t)TT * BH * 2);   // block-major
  unsigned short* hseq1 = (unsigned short*)alloc((size_t)TT * BH * 2);   // block-major
  unsigned short* hs_all = (unsigned short*)alloc((size_t)4160 * HH * 2);// row-major
  unsigned short* Xseq = (unsigned short*)alloc((size_t)TT * BE * 2);    // block-major
  unsigned short* Woutb = (unsigned short*)alloc((size_t)VV * HH * 2);

  // 1) zero read-before-write state: [flags0|flags1|h0seq slot0] and hseq1 slot0
  hipLaunchKernelGGL(zero2_k, dim3(40), dim3(256), 0, stream,
                     (uint4*)flags0, (int)((128 * 128 * 2 + BH * 2) / 16),
                     (uint4*)hseq1, (int)((BH * 2) / 16));
  // 2) convert Wout to bf16
  hipLaunchKernelGGL(cvt1_k, dim3(4096), dim3(256), 0, stream, (const float4*)Wout,
                     (u16x4*)Woutb, VV * HH / 4);
  // 3) embeddings + pos -> Xseq (block-major records)
  hipLaunchKernelGGL(embed_k, dim3(MROWS), dim3(256), 0, stream, captions, etab, pos, Xseq);
  // 4) persistent recurrence (fused X-side; no G0pre)
  hipLaunchKernelGGL(lstm_persist, dim3(NBLK), dim3(256), 0, stream, Whh0, Wih0, Wih1, Whh1,
                     bih0, bhh0, bih1, bhh1, Xseq, h0seq, hseq1, hs_all, flags0, flags1);
  // 5) projection (T4+T2+T5, fused t0-zero)
  hipLaunchKernelGGL(proj_gemm, dim3(2000), dim3(512), 0, stream, hs_all + (size_t)BH,
                     Woutb, bout, out);
}

// Round 19
// 1229.841 us; speedup vs baseline: 1.0447x; 1.0113x over previous
//
#include <hip/hip_runtime.h>
#include <hip/hip_bf16.h>
#include <math.h>

typedef __attribute__((ext_vector_type(4))) float f32x4;
typedef __attribute__((ext_vector_type(8))) short s16x8;
typedef __attribute__((ext_vector_type(4))) unsigned short u16x4;

#define MFMA16(a, b, c) __builtin_amdgcn_mfma_f32_16x16x32_bf16(a, b, c, 0, 0, 0)

static constexpr int BB = 32, TT = 128, EE = 512, HH = 1024, VV = 32000;
static constexpr int FH = 4 * HH;           // 4096 gate rows
static constexpr int MROWS = (TT - 1) * BB; // 4064 valid rows
static constexpr int BH = BB * HH;          // 32768
static constexpr int BE = BB * EE;          // 16384
static constexpr int NBLK = 256;            // recurrence grid

__device__ __forceinline__ unsigned short f2bf(float f) {
  unsigned int u = __float_as_uint(f);
  u = (u + 0x7FFFu + ((u >> 16) & 1u)) >> 16;
  return (unsigned short)u;
}
__device__ __forceinline__ float sigf(float x) { return 1.f / (1.f + __expf(-x)); }

__device__ __forceinline__ s16x8 pack8f(const float* p) {
  float4 x = *(const float4*)p;
  float4 y = *(const float4*)(p + 4);
  s16x8 r;
  r[0] = (short)f2bf(x.x); r[1] = (short)f2bf(x.y);
  r[2] = (short)f2bf(x.z); r[3] = (short)f2bf(x.w);
  r[4] = (short)f2bf(y.x); r[5] = (short)f2bf(y.y);
  r[6] = (short)f2bf(y.z); r[7] = (short)f2bf(y.w);
  return r;
}

__device__ __forceinline__ void gl_lds16(const void* g, void* l) {
  __builtin_amdgcn_global_load_lds(
      (const __attribute__((address_space(1))) unsigned int*)g,
      (__attribute__((address_space(3))) unsigned int*)l, 16, 0, 0);
}

__device__ __forceinline__ unsigned ldflag(const unsigned int* p) {
  return __hip_atomic_load(p, __ATOMIC_RELAXED, __HIP_MEMORY_SCOPE_AGENT);
}

#define FSTRIDE 32  // one 128B line per flag (round-16 measured best)

// ---------------- zero / convert / embed ----------------

__global__ void zero2_k(uint4* __restrict__ p0, int n0, uint4* __restrict__ p1, int n1) {
  int i = blockIdx.x * blockDim.x + threadIdx.x;
  int stride = gridDim.x * blockDim.x;
  uint4 z = {0u, 0u, 0u, 0u};
  for (int k = i; k < n0; k += stride) p0[k] = z;
  for (int k = i; k < n1; k += stride) p1[k] = z;
}

__global__ void cvt1_k(const float4* __restrict__ a, u16x4* __restrict__ ao, int na4) {
  int i = blockIdx.x * blockDim.x + threadIdx.x;
  int stride = gridDim.x * blockDim.x;
  for (int k = i; k < na4; k += stride) {
    float4 v = a[k];
    u16x4 o;
    o[0] = f2bf(v.x); o[1] = f2bf(v.y); o[2] = f2bf(v.z); o[3] = f2bf(v.w);
    ao[k] = o;
  }
}

// Embeddings in block-major record layout: X[t][e>>3][b][e&7]
__global__ __launch_bounds__(256) void embed_k(const int* __restrict__ captions,
                                               const float* __restrict__ etab,
                                               const float* __restrict__ pos,
                                               unsigned short* __restrict__ Xseq) {
  const int m = blockIdx.x;  // 0..4063 : t*32 + b, t < 127
  const int t = m >> 5, b = m & 31;
  const int tok = captions[b * TT + t];
  const float* er = etab + (size_t)tok * EE;
  unsigned short* xt = Xseq + (size_t)t * BE;
  for (int e = threadIdx.x; e < EE; e += 256)
    xt[(e >> 3) * 256 + b * 8 + (e & 7)] = f2bf(er[e] + pos[e]);
}

// ---------------- projection GEMM: T4 counted-vmcnt + T2 swizzle + T5 ------
// j==0 blocks also zero out[:,0,:] (fused epilogue).

__global__ __launch_bounds__(512, 1) void proj_gemm(const unsigned short* __restrict__ hsA,
                                                    const unsigned short* __restrict__ Woutb,
                                                    const float* __restrict__ bout,
                                                    float* __restrict__ out) {
  __shared__ unsigned short As[2][256 * 64];  // 64KB
  __shared__ unsigned short Bs[2][256 * 64];  // 64KB
  const int tid = threadIdx.x;
  const int lane = tid & 63, wave = tid >> 6;    // 8 waves
  const int wm = wave & 1, wn = wave >> 1;       // wm 0..1, wn 0..3
  const int T = blockIdx.x;
  const int bq = T & 15;
  const int j = 2 * (bq & 7) + (bq >> 3);        // XCD-pinned m-stripe pair
  const int n = T >> 4;                          // 0..124
  const int m0 = j * 256, n0 = n * 256;
  const int sch = (((lane & 7) ^ ((lane >> 3) & 7)) * 8);  // swizzled source slot
  const int rbase = tid >> 3;                    // staging row (this thread)
  f32x4 acc[8][4] = {};

  auto stageP = [&](int ks, int buf) {
    const int k0 = ks * 64;
#pragma unroll
    for (int i = 0; i < 4; ++i) {
      const int r = rbase + i * 64;
      gl_lds16(&hsA[(size_t)(m0 + r) * HH + k0 + sch], &As[buf][(wave * 64 + i * 512) * 8]);
      gl_lds16(&Woutb[(size_t)(n0 + r) * HH + k0 + sch], &Bs[buf][(wave * 64 + i * 512) * 8]);
    }
  };

  stageP(0, 0);

  for (int ks = 0; ks < 16; ++ks) {
    const int cur = ks & 1;
    if (ks < 15) {
      stageP(ks + 1, cur ^ 1);
      asm volatile("s_waitcnt vmcnt(8)" ::: "memory");
    } else {
      asm volatile("s_waitcnt vmcnt(0)" ::: "memory");
    }
    __builtin_amdgcn_s_barrier();
    __builtin_amdgcn_s_setprio(1);
#pragma unroll
    for (int kk = 0; kk < 64; kk += 32) {
      s16x8 af[8], bf[4];
#pragma unroll
      for (int f = 0; f < 8; ++f) {
        const int Ra = wm * 128 + f * 16 + (lane & 15);
        const int slot = (kk >> 3) + (lane >> 4);
        af[f] = *(const s16x8*)(&As[cur][Ra * 64 + ((slot ^ (Ra & 7)) * 8)]);
      }
#pragma unroll
      for (int f = 0; f < 4; ++f) {
        const int Rb = wn * 64 + f * 16 + (lane & 15);
        const int slot = (kk >> 3) + (lane >> 4);
        bf[f] = *(const s16x8*)(&Bs[cur][Rb * 64 + ((slot ^ (Rb & 7)) * 8)]);
      }
#pragma unroll
      for (int mi = 0; mi < 8; ++mi)
#pragma unroll
        for (int ni = 0; ni < 4; ++ni)
          acc[mi][ni] = MFMA16(af[mi], bf[ni], acc[mi][ni]);
    }
    __builtin_amdgcn_s_setprio(0);
    asm volatile("" ::: "memory");
    __builtin_amdgcn_s_barrier();
  }

#pragma unroll
  for (int mi = 0; mi < 8; ++mi) {
#pragma unroll
    for (int ni = 0; ni < 4; ++ni) {
      const int col = n0 + wn * 64 + ni * 16 + (lane & 15);
      const float bs = bout[col];
      const int mbase = m0 + wm * 128 + mi * 16 + (lane >> 4) * 4;
#pragma unroll
      for (int r2 = 0; r2 < 4; ++r2) {
        const int m = mbase + r2;
        if (m < MROWS) {
          const int tt = m >> 5, b2 = m & 31;
          out[((size_t)b2 * TT + tt + 1) * VV + col] = acc[mi][ni][r2] + bs;
        }
      }
    }
  }

  if (j == 0) {
    for (int i = tid; i < 32 * 256; i += 512) {
      const int b2 = i >> 8, c = i & 255;
      out[(size_t)b2 * TT * VV + n0 + c] = 0.f;
    }
  }
}

// ---------------- persistent 2-layer LSTM, fused X-side (no G0pre) --------
// Round-18 structure; ONE change: L1's row-major hs_all scatter moved AFTER
// the flag publish (off the serial critical path — its 256 write-allocated
// lines drain during the next poll/compute; only the next kernel reads it).

__global__ __launch_bounds__(256, 1) void lstm_persist(
    const float* __restrict__ Whh0f, const float* __restrict__ Wih0f,
    const float* __restrict__ Wih1f, const float* __restrict__ Whh1f,
    const float* __restrict__ bih0, const float* __restrict__ bhh0,
    const float* __restrict__ bih1, const float* __restrict__ bhh1,
    const unsigned short* __restrict__ Xseq,
    unsigned short* __restrict__ h0seq, unsigned short* __restrict__ hseq1,
    unsigned short* __restrict__ hs_all,
    unsigned int* __restrict__ flags0, unsigned int* __restrict__ flags1) {
  __shared__ float parts[4][2][2][16][16];  // 8KB
  const int bid = blockIdx.x;
  const int layer = bid >> 7;
  const int blk = bid & 127;
  const int tid = threadIdx.x, lane = tid & 63, wave = tid >> 6;
  const int jb = blk * 8;
  const int colIdx = lane & 15;
  const int kq = lane >> 4;
  const int wrow0 = (colIdx >> 3) * HH + jb + (colIdx & 7);

  const int cb = tid >> 3, cjj = tid & 7;
  float creg = 0.f;
  float bsum[4];
  if (layer == 0) {
#pragma unroll
    for (int gi = 0; gi < 4; ++gi)
      bsum[gi] = bih0[gi * HH + jb + cjj] + bhh0[gi * HH + jb + cjj];
  } else {
#pragma unroll
    for (int gi = 0; gi < 4; ++gi)
      bsum[gi] = bih1[gi * HH + jb + cjj] + bhh1[gi * HH + jb + cjj];
  }

  // ---- recurrent weights into registers (fp32 -> bf16) ----
  s16x8 wreg[16][2];   // h-side
  s16x8 wregx[4][2];   // X-side (L0 only, K=512)
  const int kb = (layer == 0) ? wave * 256 : (wave & 1) * 512;
  const int kbx = wave * 128;
  if (layer == 0) {
#pragma unroll
    for (int fi = 0; fi < 2; ++fi) {
      const float* wp = Whh0f + (size_t)(wrow0 + fi * 2 * HH) * HH + kb + kq * 8;
#pragma unroll
      for (int ks = 0; ks < 8; ++ks) wreg[ks][fi] = pack8f(wp + ks * 32);
      const float* wpx = Wih0f + (size_t)(wrow0 + fi * 2 * HH) * EE + kbx + kq * 8;
#pragma unroll
      for (int ks = 0; ks < 4; ++ks) wregx[ks][fi] = pack8f(wpx + ks * 32);
    }
  } else {
    const float* Wsrc = (wave < 2) ? Wih1f : Whh1f;
#pragma unroll
    for (int fi = 0; fi < 2; ++fi) {
      const float* wp = Wsrc + (size_t)(wrow0 + fi * 2 * HH) * HH + kb + kq * 8;
#pragma unroll
      for (int ks = 0; ks < 16; ++ks) wreg[ks][fi] = pack8f(wp + ks * 32);
    }
  }

  const int frag_off = (kb >> 3) * 256 + kq * 256 + (lane & 15) * 8;
  const int frag_offX = (wave * 16 + kq) * 256 + (lane & 15) * 8;

  if (layer == 0) {
    // =================== L0 chain ===================
    for (int t = 0; t < TT - 1; ++t) {
      if (t > 0 && wave == 0) {
        const unsigned tgt = (unsigned)t;
        for (;;) {
          unsigned a = ldflag(&flags0[(lane * 2 + 0) * FSTRIDE]);
          unsigned b = ldflag(&flags0[(lane * 2 + 1) * FSTRIDE]);
          if (__all(min(a, b) >= tgt)) break;
          __builtin_amdgcn_s_sleep(1);
        }
      }
      __syncthreads();
      asm volatile("" ::: "memory");

      const unsigned short* x0 = Xseq + (size_t)t * BE + frag_offX;
      const unsigned short* x1 = x0 + 128;
      const unsigned short* a0 = h0seq + (size_t)t * BH + frag_off;
      const unsigned short* a1 = a0 + 128;
      f32x4 acc00 = {}, acc01 = {}, acc10 = {}, acc11 = {};
#pragma unroll
      for (int ks = 0; ks < 4; ++ks) {
        s16x8 xv0 = *(const s16x8*)(x0 + ks * 1024);
        s16x8 xv1 = *(const s16x8*)(x1 + ks * 1024);
        acc00 = MFMA16(xv0, wregx[ks][0], acc00);
        acc01 = MFMA16(xv0, wregx[ks][1], acc01);
        acc10 = MFMA16(xv1, wregx[ks][0], acc10);
        acc11 = MFMA16(xv1, wregx[ks][1], acc11);
      }
#pragma unroll
      for (int ks = 0; ks < 8; ++ks) {
        s16x8 av0 = *(const s16x8*)(a0 + ks * 1024);
        s16x8 av1 = *(const s16x8*)(a1 + ks * 1024);
        acc00 = MFMA16(av0, wreg[ks][0], acc00);
        acc01 = MFMA16(av0, wreg[ks][1], acc01);
        acc10 = MFMA16(av1, wreg[ks][0], acc10);
        acc11 = MFMA16(av1, wreg[ks][1], acc11);
      }
#pragma unroll
      for (int r = 0; r < 4; ++r) {
        parts[wave][0][0][kq * 4 + r][colIdx] = acc00[r];
        parts[wave][0][1][kq * 4 + r][colIdx] = acc01[r];
        parts[wave][1][0][kq * 4 + r][colIdx] = acc10[r];
        parts[wave][1][1][kq * 4 + r][colIdx] = acc11[r];
      }
      __syncthreads();
      float g[4];
#pragma unroll
      for (int gi = 0; gi < 4; ++gi) {
        float s = bsum[gi];
        const int fi = gi >> 1, c = (gi & 1) * 8 + cjj;
#pragma unroll
        for (int w4 = 0; w4 < 4; ++w4) s += parts[w4][cb >> 4][fi][cb & 15][c];
        g[gi] = s;
      }
      const float i_ = sigf(g[0]), f_ = sigf(g[1]), gg = tanhf(g[2]), o_ = sigf(g[3]);
      creg = f_ * creg + i_ * gg;
      *(volatile unsigned short*)&h0seq[(size_t)(t + 1) * BH + blk * 256 + tid] =
          f2bf(o_ * tanhf(creg));

      asm volatile("s_waitcnt vmcnt(0)" ::: "memory");
      __syncthreads();
      if (tid == 0) *(volatile unsigned int*)&flags0[blk * FSTRIDE] = (unsigned)(t + 1);
    }
  } else {
    // =================== L1 chain ===================
    for (int t = 1; t < TT; ++t) {
      if (wave == 0) {
        const unsigned t0 = (unsigned)t, t1 = (unsigned)(t - 1);
        for (;;) {
          unsigned a0f = ldflag(&flags0[(lane * 2 + 0) * FSTRIDE]);
          unsigned b0f = ldflag(&flags0[(lane * 2 + 1) * FSTRIDE]);
          unsigned a1f = ldflag(&flags1[(lane * 2 + 0) * FSTRIDE]);
          unsigned b1f = ldflag(&flags1[(lane * 2 + 1) * FSTRIDE]);
          bool ok = (min(a0f, b0f) >= t0) && (min(a1f, b1f) >= t1);
          if (__all(ok)) break;
          __builtin_amdgcn_s_sleep(1);
        }
      }
      __syncthreads();
      asm volatile("" ::: "memory");

      const unsigned short* base = (wave < 2)
                                       ? (h0seq + (size_t)t * BH)         // h0(t-1)
                                       : (hseq1 + (size_t)(t - 1) * BH);  // h1(t-2)
      const unsigned short* a0 = base + frag_off;
      const unsigned short* a1 = a0 + 128;
      f32x4 acc00 = {}, acc01 = {}, acc10 = {}, acc11 = {};
#pragma unroll
      for (int ks = 0; ks < 16; ++ks) {
        s16x8 av0 = *(const s16x8*)(a0 + ks * 1024);
        s16x8 av1 = *(const s16x8*)(a1 + ks * 1024);
        acc00 = MFMA16(av0, wreg[ks][0], acc00);
        acc01 = MFMA16(av0, wreg[ks][1], acc01);
        acc10 = MFMA16(av1, wreg[ks][0], acc10);
        acc11 = MFMA16(av1, wreg[ks][1], acc11);
      }
#pragma unroll
      for (int r = 0; r < 4; ++r) {
        parts[wave][0][0][kq * 4 + r][colIdx] = acc00[r];
        parts[wave][0][1][kq * 4 + r][colIdx] = acc01[r];
        parts[wave][1][0][kq * 4 + r][colIdx] = acc10[r];
        parts[wave][1][1][kq * 4 + r][colIdx] = acc11[r];
      }
      __syncthreads();
      float g[4];
#pragma unroll
      for (int gi = 0; gi < 4; ++gi) {
        float s = bsum[gi];
        const int fi = gi >> 1, c = (gi & 1) * 8 + cjj;
#pragma unroll
        for (int w4 = 0; w4 < 4; ++w4) s += parts[w4][cb >> 4][fi][cb & 15][c];
        g[gi] = s;
      }
      const float i_ = sigf(g[0]), f_ = sigf(g[1]), gg = tanhf(g[2]), o_ = sigf(g[3]);
      creg = f_ * creg + i_ * gg;
      const unsigned short hv = f2bf(o_ * tanhf(creg));
      // critical-path publish: block-major only
      *(volatile unsigned short*)&hseq1[(size_t)t * BH + blk * 256 + tid] = hv;
      asm volatile("s_waitcnt vmcnt(0)" ::: "memory");
      __syncthreads();
      if (tid == 0) *(volatile unsigned int*)&flags1[blk * FSTRIDE] = (unsigned)t;
      // off-path: row-major scatter for the projection (drains lazily)
      hs_all[(size_t)t * BH + (size_t)cb * HH + jb + cjj] = hv;
    }
  }
}

// ---------------- host ----------------

extern "C" void kernel_launch(void* const* d_in, const int* in_sizes, int n_in,
                              void* d_out, int out_size, void* d_ws, size_t ws_size,
                              hipStream_t stream) {
  const int* captions = (const int*)d_in[1];
  const float* etab = (const float*)d_in[2];
  const float* pos = (const float*)d_in[3];
  const float* Wih0 = (const float*)d_in[4];
  const float* Whh0 = (const float*)d_in[5];
  const float* bih0 = (const float*)d_in[6];
  const float* bhh0 = (const float*)d_in[7];
  const float* Wih1 = (const float*)d_in[8];
  const float* Whh1 = (const float*)d_in[9];
  const float* bih1 = (const float*)d_in[10];
  const float* bhh1 = (const float*)d_in[11];
  const float* Wout = (const float*)d_in[12];
  const float* bout = (const float*)d_in[13];
  float* out = (float*)d_out;

  char* w = (char*)d_ws;
  auto alloc = [&](size_t bytes) {
    char* p = w;
    w += (bytes + 255) & ~(size_t)255;
    return p;
  };
  // layout: flags0(16KB) flags1(16KB) h0seq hseq1 hs_all Xseq Woutb
  unsigned int* flags0 = (unsigned int*)alloc(128 * 128);
  unsigned int* flags1 = (unsigned int*)alloc(128 * 128);
  unsigned short* h0seq = (unsigned short*)alloc((size_t)TT * BH * 2);   // block-major
  unsigned short* hseq1 = (unsigned short*)alloc((size_t)TT * BH * 2);   // block-major
  unsigned short* hs_all = (unsigned short*)alloc((size_t)4160 * HH * 2);// row-major
  unsigned short* Xseq = (unsigned short*)alloc((size_t)TT * BE * 2);    // block-major
  unsigned short* Woutb = (unsigned short*)alloc((size_t)VV * HH * 2);

  // 1) zero read-before-write state: [flags0|flags1|h0seq slot0] and hseq1 slot0
  hipLaunchKernelGGL(zero2_k, dim3(40), dim3(256), 0, stream,
                     (uint4*)flags0, (int)((128 * 128 * 2 + BH * 2) / 16),
                     (uint4*)hseq1, (int)((BH * 2) / 16));
  // 2) convert Wout to bf16
  hipLaunchKernelGGL(cvt1_k, dim3(4096), dim3(256), 0, stream, (const float4*)Wout,
                     (u16x4*)Woutb, VV * HH / 4);
  // 3) embeddings + pos -> Xseq (block-major records)
  hipLaunchKernelGGL(embed_k, dim3(MROWS), dim3(256), 0, stream, captions, etab, pos, Xseq);
  // 4) persistent recurrence (fused X-side; deferred hs_all scatter)
  hipLaunchKernelGGL(lstm_persist, dim3(NBLK), dim3(256), 0, stream, Whh0, Wih0, Wih1, Whh1,
                     bih0, bhh0, bih1, bhh1, Xseq, h0seq, hseq1, hs_all, flags0, flags1);
  // 5) projection (T4+T2+T5, fused t0-zero)
  hipLaunchKernelGGL(proj_gemm, dim3(2000), dim3(512), 0, stream, hs_all + (size_t)BH,
                     Woutb, bout, out);
}